// Round 17
// baseline (238.553 us; speedup 1.0000x reference)
//
#include <hip/hip_runtime.h>
#include <cstdint>

#define SEQ     3120
#define SPAD    3200
#define DIM     1536
#define NQKV    4608
#define HEADS   12
#define HD      128
#define SPATIAL 390
#define EPSV    1e-5f
#define KVBLK   128
#define NTILES  25
#define NEGBIG  (-1e30f)
// 1/sqrt(128) * log2(e): attention scores computed in log2 domain.
// FIXED-scale softmax (no running max): |s| <= ~12 in log2 domain, so
// exp2(s) <= 4096 and sum <= ~1e7 -- safely inside fp32; softmax is exactly
// scale-invariant, and bf16 relative precision is scale-free.
#define QSCALE  (0.08838834764831845f * 1.4426950408889634f)
#define CROW(r, hi) ((((r) & 3) + 8 * ((r) >> 2)) + 4 * (hi))

typedef unsigned short u16;
typedef short s16x8 __attribute__((ext_vector_type(8)));
typedef float f32x4 __attribute__((ext_vector_type(4)));
typedef float f32x16 __attribute__((ext_vector_type(16)));

__device__ __forceinline__ u16 f2bf(float f) {
  union { float f; unsigned u; } v; v.f = f;
  unsigned r = v.u + 0x7FFFu + ((v.u >> 16) & 1u);
  return (u16)(r >> 16);
}
__device__ __forceinline__ float bf2f(u16 b) {
  union { unsigned u; float f; } v; v.u = ((unsigned)b) << 16;
  return v.f;
}
__device__ __forceinline__ unsigned cvtpk(float lo, float hi) {
  unsigned r;
  asm("v_cvt_pk_bf16_f32 %0, %1, %2" : "=v"(r) : "v"(lo), "v"(hi));
  return r;
}
// async global->LDS, 16B per lane. LDS dest = wave-uniform base + lane*16.
__device__ __forceinline__ void gload16(const void* g, const void* l) {
  __builtin_amdgcn_global_load_lds(
      (const __attribute__((address_space(1))) unsigned*)g,
      (__attribute__((address_space(3))) unsigned*)(uintptr_t)l,
      16, 0, 0);
}

// ------- 1+2 fused prep: blocks [0,4800) convert x + biascat; -------------
//         blocks [4800,7104) transpose+convert the 4 weight matrices.
__global__ __launch_bounds__(256) void k_prep(
    const float* __restrict__ x, const float* __restrict__ bq,
    const float* __restrict__ bk, const float* __restrict__ bv,
    const float* __restrict__ Wq, const float* __restrict__ Wk,
    const float* __restrict__ Wv, const float* __restrict__ Wo,
    u16* __restrict__ xb, float* __restrict__ bcat,
    u16* __restrict__ WtAll, u16* __restrict__ WoT) {
  __shared__ float t[64][65];
  const int bid = blockIdx.x;
  if (bid < 4800) {
    // ---- convert x fp32 -> bf16, pad rows [SEQ,SPAD) with 0; biascat -----
    if (bid == 0) {
      for (int j = threadIdx.x; j < NQKV; j += 256)
        bcat[j] = (j < DIM) ? bq[j] : (j < 2 * DIM) ? bk[j - DIM] : bv[j - 2 * DIM];
    }
    const int i = (bid * 256 + threadIdx.x) * 4;
    if (i >= SPAD * DIM) return;
    const int row = i / DIM;
    float4 v = make_float4(0.f, 0.f, 0.f, 0.f);
    if (row < SEQ) v = *(const float4*)(x + i);
    const unsigned lo = (unsigned)f2bf(v.x) | ((unsigned)f2bf(v.y) << 16);
    const unsigned hi = (unsigned)f2bf(v.z) | ((unsigned)f2bf(v.w) << 16);
    *(uint2*)(xb + i) = make_uint2(lo, hi);
  } else {
    // ---- transpose weights: Wt[n][k] = W[k][n], 64x64 tiles --------------
    const int tb = bid - 4800;              // 0..2303
    const int wsel = tb / 576;              // 576 = 24*24
    const int rem = tb - wsel * 576;
    const int byi = rem / 24, bxi = rem - (rem / 24) * 24;
    const float* W = (wsel == 0) ? Wq : (wsel == 1) ? Wk : (wsel == 2) ? Wv : Wo;
    const int k0 = bxi * 64, n0 = byi * 64;
    const int c = threadIdx.x & 63, r4 = threadIdx.x >> 6;
#pragma unroll
    for (int rr = 0; rr < 64; rr += 4)
      t[r4 + rr][c] = W[(size_t)(k0 + r4 + rr) * DIM + n0 + c];
    __syncthreads();
    u16* Wt = (wsel < 3) ? (WtAll + (size_t)wsel * DIM * DIM) : WoT;
    const int kp = threadIdx.x & 31;
    const int r8 = threadIdx.x >> 5;
#pragma unroll
    for (int rr = 0; rr < 64; rr += 8) {
      const int n = r8 + rr;
      const unsigned v = (unsigned)f2bf(t[2 * kp][n]) |
                         ((unsigned)f2bf(t[2 * kp + 1][n]) << 16);
      *(unsigned*)&Wt[(size_t)(n0 + n) * DIM + k0 + 2 * kp] = v;
    }
  }
}

// ------- 4/8. bf16 MFMA GEMM, BK=64, dbuf + counted vmcnt (attn pattern) --
template <int OUT_BF16>
__global__ __launch_bounds__(256) void k_gemm(const u16* __restrict__ A,
                                              const u16* __restrict__ Bt,
                                              const float* __restrict__ bias,
                                              void* __restrict__ Cout,
                                              int N, int K, int storeMmax,
                                              int nbx) {
  __shared__ short As[2][8192];  // [128][64] swizzled
  __shared__ short Bs[2][8192];
  const int nwg = gridDim.x;
  const int q = nwg >> 3, r = nwg & 7;
  const int xcd = blockIdx.x & 7, idx = blockIdx.x >> 3;
  const int swz = (xcd < r ? xcd * (q + 1) : r * (q + 1) + (xcd - r) * q) + idx;
  const int bxi = swz % nbx, byi = swz / nbx;
  const int brow = byi * 128, bcol = bxi * 128;

  const int tid = threadIdx.x;
  const int lane = tid & 63, wv = tid >> 6;
  const int l15 = lane & 15, g = lane >> 4;
  const int wr = wv >> 1, wc = wv & 1;

  const f32x4 z4 = {0.f, 0.f, 0.f, 0.f};
  f32x4 acc[4][4];
#pragma unroll
  for (int m = 0; m < 4; ++m)
#pragma unroll
    for (int n = 0; n < 4; ++n) acc[m][n] = z4;

  const u16* Ap[4];
  const u16* Bp[4];
  const int sch = ((lane & 7) ^ ((lane >> 3) & 7)) * 8;
#pragma unroll
  for (int it = 0; it < 4; ++it) {
    const int row = it * 32 + wv * 8 + (lane >> 3);
    Ap[it] = A + (size_t)(brow + row) * K + sch;
    Bp[it] = Bt + (size_t)(bcol + row) * K + sch;
  }
  auto stage = [&](int T, int B) {
    const int k0 = T * 64;
#pragma unroll
    for (int it = 0; it < 4; ++it) {
      gload16(Ap[it] + k0, &As[B][(it * 32 + wv * 8) * 64]);
      gload16(Bp[it] + k0, &Bs[B][(it * 32 + wv * 8) * 64]);
    }
  };

  const int NK = K >> 6;
  stage(0, 0);

  for (int t = 0; t < NK; ++t) {
    const int b = t & 1;
    if (t + 1 < NK) {
      stage(t + 1, b ^ 1);
      asm volatile("s_waitcnt vmcnt(8)" ::: "memory");  // tile t's 8 done
    } else {
      asm volatile("s_waitcnt vmcnt(0)" ::: "memory");
    }
    __builtin_amdgcn_s_barrier();
    __builtin_amdgcn_sched_barrier(0);
#pragma unroll
    for (int kk = 0; kk < 2; ++kk) {
      s16x8 a[4], bfr[4];
#pragma unroll
      for (int m = 0; m < 4; ++m)
        a[m] = *(const s16x8*)&As[b][(wr * 64 + m * 16 + l15) * 64 +
                                     (((kk * 4 + g) ^ (l15 & 7)) * 8)];
#pragma unroll
      for (int n = 0; n < 4; ++n)
        bfr[n] = *(const s16x8*)&Bs[b][(wc * 64 + n * 16 + l15) * 64 +
                                       (((kk * 4 + g) ^ (l15 & 7)) * 8)];
#pragma unroll
      for (int m = 0; m < 4; ++m)
#pragma unroll
        for (int n = 0; n < 4; ++n)
          acc[m][n] = __builtin_amdgcn_mfma_f32_16x16x32_bf16(a[m], bfr[n], acc[m][n], 0, 0, 0);
    }
    __builtin_amdgcn_s_barrier();  // protect buf b before stage(t+2) writes it
    __builtin_amdgcn_sched_barrier(0);
  }

#pragma unroll
  for (int m = 0; m < 4; ++m) {
#pragma unroll
    for (int n = 0; n < 4; ++n) {
      const int cc = bcol + wc * 64 + n * 16 + l15;
      const float bb = bias[cc];
#pragma unroll
      for (int i = 0; i < 4; ++i) {
        const int rr = brow + wr * 64 + m * 16 + g * 4 + i;
        if (rr < storeMmax) {
          const float v = acc[m][n][i] + bb;
          if (OUT_BF16) ((u16*)Cout)[(size_t)rr * N + cc] = f2bf(v);
          else          ((float*)Cout)[(size_t)rr * N + cc] = v;
        }
      }
    }
  }
}

// ---------------- 5. per-token: rmsnorm + rope + biases (vectorized) -------
__global__ __launch_bounds__(256) void k_post(
    const u16* __restrict__ Pqkv, const float* __restrict__ freqs,
    const float* __restrict__ gq, const float* __restrict__ gk,
    const float* __restrict__ qkfb, const float* __restrict__ vfb,
    const float* __restrict__ vsb,
    u16* __restrict__ Qf, u16* __restrict__ Kf, u16* __restrict__ Vf) {
  const int s = blockIdx.x;
  const int t = threadIdx.x;
  const int fidx = s / SPATIAL;
  const int sp = s - fidx * SPATIAL;
  __shared__ float cs[64], sn[64];
  __shared__ float red[8];
  if (t < 64) {
    const float a = freqs[s * 64 + t];
    cs[t] = __cosf(a);
    sn[t] = __sinf(a);
  }
  const u16* qrow = Pqkv + (size_t)s * NQKV;
  const u16* krow = qrow + DIM;
  const u16* vrow = qrow + 2 * DIM;
  s16x8 q8, k8, v8;
  float sq = 0.f, sk = 0.f;
  if (t < 192) {
    q8 = *(const s16x8*)(qrow + 8 * t);
    k8 = *(const s16x8*)(krow + 8 * t);
    v8 = *(const s16x8*)(vrow + 8 * t);
#pragma unroll
    for (int i = 0; i < 8; ++i) {
      const float a = bf2f((u16)q8[i]); sq += a * a;
      const float b = bf2f((u16)k8[i]); sk += b * b;
    }
  }
#pragma unroll
  for (int off = 1; off < 64; off <<= 1) {
    sq += __shfl_xor(sq, off);
    sk += __shfl_xor(sk, off);
  }
  const int lane = t & 63, wv = t >> 6;
  if (lane == 0) { red[wv] = sq; red[wv + 4] = sk; }
  __syncthreads();
  sq = red[0] + red[1] + red[2] + red[3];
  sk = red[4] + red[5] + red[6] + red[7];
  const float rq = rsqrtf(sq * (1.0f / DIM) + EPSV);
  const float rk = rsqrtf(sk * (1.0f / DIM) + EPSV);
  if (t >= 192) return;
  const int d0 = 8 * t;
  float GQ[8], GK[8], FB[8], VF[8], VS[8];
  *(float4*)&GQ[0] = *(const float4*)(gq + d0);
  *(float4*)&GQ[4] = *(const float4*)(gq + d0 + 4);
  *(float4*)&GK[0] = *(const float4*)(gk + d0);
  *(float4*)&GK[4] = *(const float4*)(gk + d0 + 4);
  *(float4*)&FB[0] = *(const float4*)(qkfb + fidx * DIM + d0);
  *(float4*)&FB[4] = *(const float4*)(qkfb + fidx * DIM + d0 + 4);
  *(float4*)&VF[0] = *(const float4*)(vfb + fidx * DIM + d0);
  *(float4*)&VF[4] = *(const float4*)(vfb + fidx * DIM + d0 + 4);
  *(float4*)&VS[0] = *(const float4*)(vsb + (size_t)sp * DIM + d0);
  *(float4*)&VS[4] = *(const float4*)(vsb + (size_t)sp * DIM + d0 + 4);
  unsigned qo[4], ko[4], vo[4];
#pragma unroll
  for (int pi = 0; pi < 4; ++pi) {
    const int pin = (4 * t + pi) & 63;
    const float c = cs[pin], s_ = sn[pin];
    float xr = bf2f((u16)q8[2 * pi]) * rq * GQ[2 * pi];
    float xi = bf2f((u16)q8[2 * pi + 1]) * rq * GQ[2 * pi + 1];
    const float q0 = (xr * c - xi * s_ + FB[2 * pi]) * QSCALE;
    const float q1 = (xr * s_ + xi * c + FB[2 * pi + 1]) * QSCALE;
    qo[pi] = (unsigned)f2bf(q0) | ((unsigned)f2bf(q1) << 16);
    xr = bf2f((u16)k8[2 * pi]) * rk * GK[2 * pi];
    xi = bf2f((u16)k8[2 * pi + 1]) * rk * GK[2 * pi + 1];
    const float kk0 = xr * c - xi * s_ + FB[2 * pi];
    const float kk1 = xr * s_ + xi * c + FB[2 * pi + 1];
    ko[pi] = (unsigned)f2bf(kk0) | ((unsigned)f2bf(kk1) << 16);
    const float v0 = bf2f((u16)v8[2 * pi]) + VF[2 * pi] + VS[2 * pi];
    const float v1 = bf2f((u16)v8[2 * pi + 1]) + VF[2 * pi + 1] + VS[2 * pi + 1];
    vo[pi] = (unsigned)f2bf(v0) | ((unsigned)f2bf(v1) << 16);
  }
  *(uint4*)(Qf + (size_t)s * DIM + d0) = make_uint4(qo[0], qo[1], qo[2], qo[3]);
  *(uint4*)(Kf + (size_t)s * DIM + d0) = make_uint4(ko[0], ko[1], ko[2], ko[3]);
  *(uint4*)(Vf + (size_t)s * DIM + d0) = make_uint4(vo[0], vo[1], vo[2], vo[3]);
}

// ---------------- 6. V transpose: Vf[s][1536] -> Vt[dglob][SPAD] -----------
__global__ __launch_bounds__(256) void k_transpose_v(const u16* __restrict__ Vf,
                                                     u16* __restrict__ Vt) {
  __shared__ u16 tile[64][65];
  const int s0 = blockIdx.x * 64, c0 = blockIdx.y * 64;
  const int c = threadIdx.x & 63, r4 = threadIdx.x >> 6;
#pragma unroll
  for (int rr = 0; rr < 64; rr += 4) {
    const int s = s0 + r4 + rr;
    tile[r4 + rr][c] = (s < SEQ) ? Vf[(size_t)s * DIM + c0 + c] : (u16)0;
  }
  __syncthreads();
#pragma unroll
  for (int rr = 0; rr < 64; rr += 4) {
    const int dglob = c0 + r4 + rr;
    Vt[(size_t)dglob * SPAD + s0 + c] = tile[c][r4 + rr];
  }
}

// ---------------- 7. flash attention: KVBLK=128, 2-stage group pipeline ----
// 1D grid 240: gb = (bid&7)*30 + (bid>>3); h = gb/20, bx = gb%20 (R13:
// FETCH 80->18MB). Fixed-scale softmax is order-free; per 128-key tile, 4
// independent 32-key groups. T15 pipeline: QK(grp+1) MFMA chain is issued
// BEFORE softmax/PV of grp, so the two dependent MFMA chains interleave and
// VALU softmax fills the chain-stall slots. Fully unrolled (stc/stn are SSA
// -- no runtime indexing, rule #20). PV ascending key order -> bit-identical.
// K LDS [128 key][16 ch][8] ch^=key&15; V^T LDS [128 d][16 ch][8] ch^=d&15.
__global__ __launch_bounds__(320, 2) void k_attn(const u16* __restrict__ Qf,
                                                 const u16* __restrict__ Kf,
                                                 const u16* __restrict__ Vt,
                                                 u16* __restrict__ AttO) {
  __shared__ short Ks[2][16384];  // [128 key][16 chunk][8]
  __shared__ short Vs[2][16384];  // [128 d][16 chunk][8]
  const int bid = blockIdx.x;
  const int gb = (bid & 7) * 30 + (bid >> 3);
  const int h = gb / 20;
  const int bx = gb - h * 20;
  const int tid = threadIdx.x;
  const int lane = tid & 63, w = tid >> 6;     // w in 0..4
  const int l31 = lane & 31, hi = lane >> 5;
  const int qrow = bx * 160 + w * 32 + l31;

  // Q B-frags: qb[s] = Q[qrow][16s + 8hi + j]
  s16x8 qb[8];
  {
    const u16* qp = Qf + (size_t)qrow * DIM + h * HD + hi * 8;
#pragma unroll
    for (int s = 0; s < 8; ++s) qb[s] = *(const s16x8*)(qp + s * 16);
  }

  f32x16 o[4];
#pragma unroll
  for (int d = 0; d < 4; ++d)
#pragma unroll
    for (int r = 0; r < 16; ++r) o[d][r] = 0.f;
  float sl = 0.f;

  // staging pointers (warps 0..3: each stages 32 K-rows + 32 V-rows)
  const u16* Kp[8];
  const u16* Vp[8];
  if (w < 4) {
#pragma unroll
    for (int it = 0; it < 8; ++it) {
      const int krow = w * 32 + it * 4 + (lane >> 4);
      const int kch = (lane & 15) ^ (krow & 15);
      Kp[it] = Kf + (size_t)krow * DIM + h * HD + kch * 8;
      const int vrow = w * 32 + it * 4 + (lane >> 4);
      const int vch = (lane & 15) ^ (vrow & 15);
      Vp[it] = Vt + (size_t)(h * HD + vrow) * SPAD + vch * 8;
    }
  }
  auto stage = [&](int T, int B) {
    const size_t kof = (size_t)T * KVBLK * DIM;
    const int vof = T * KVBLK;
#pragma unroll
    for (int it = 0; it < 8; ++it) {
      gload16(Kp[it] + kof, &Ks[B][(w * 32 + it * 4) * 128]);
      gload16(Vp[it] + vof, &Vs[B][(w * 32 + it * 4) * 128]);
    }
  };

  // one group's QK: S^T = K Q over keys [grp*32, grp*32+32)
  auto qk = [&](const short* Kb, int grp) -> f32x16 {
    f32x16 st;
#pragma unroll
    for (int r = 0; r < 16; ++r) st[r] = 0.f;
#pragma unroll
    for (int s = 0; s < 8; ++s) {
      const s16x8 ka = *(const s16x8*)&Kb[(grp * 32 + l31) * 128 +
                                          (((2 * s + hi) ^ (lane & 15)) * 8)];
      st = __builtin_amdgcn_mfma_f32_32x32x16_bf16(ka, qb[s], st, 0, 0, 0);
    }
    return st;
  };

  if (w < 4) {
    asm volatile("s_waitcnt vmcnt(0)" ::: "memory");
    stage(0, 0);
  }

  for (int t = 0; t < NTILES; ++t) {
    const int b = t & 1;
    if (w < 4) {
      if (t + 1 < NTILES) {
        stage(t + 1, b ^ 1);
        asm volatile("s_waitcnt vmcnt(16)" ::: "memory");  // tile t's 16 done
      } else {
        asm volatile("s_waitcnt vmcnt(0)" ::: "memory");
      }
    }
    __builtin_amdgcn_s_barrier();
    __builtin_amdgcn_sched_barrier(0);

    const short* Kb = &Ks[b][0];
    const bool lastT = (t == NTILES - 1);

    // 2-stage pipeline over the 4 groups: QK(grp+1) || {softmax+PV}(grp)
    f32x16 stc = qk(Kb, 0);
#pragma unroll
    for (int grp = 0; grp < 4; ++grp) {
      f32x16 stn;
      __builtin_amdgcn_s_setprio(1);
      if (grp < 3) stn = qk(Kb, grp + 1);   // independent chain, issued early
      __builtin_amdgcn_s_setprio(0);

      if (lastT) {  // tile 24: keys >= 3120 invalid
        if (grp == 1) {
#pragma unroll
          for (int r = 8; r < 16; ++r) stc[r] = NEGBIG;   // keys 3120..3135
        } else if (grp >= 2) {
#pragma unroll
          for (int r = 0; r < 16; ++r) stc[r] = NEGBIG;   // keys 3136..3199
        }
      }
      // P = exp2(S): fixed scale, lane-local sums, pack bf16
      unsigned W[8];
      float p0s = 0.f, p1s = 0.f;
#pragma unroll
      for (int i = 0; i < 8; ++i) {
        const float p0 = exp2f(stc[2 * i]);
        const float p1 = exp2f(stc[2 * i + 1]);
        p0s += p0; p1s += p1;
        W[i] = cvtpk(p0, p1);
      }
      sl += p0s + p1s;

      // O += P V  (partner exchange via permlane32_swap, VALU not LDS)
      __builtin_amdgcn_s_setprio(1);
#pragma unroll
      for (int s2 = 0; s2 < 2; ++s2) {
        const int S = grp * 2 + s2;        // global key-slice (16 keys)
        unsigned a0 = W[s2 * 4 + 0], b0 = W[s2 * 4 + 2];
        unsigned a1 = W[s2 * 4 + 1], b1 = W[s2 * 4 + 3];
        asm volatile("v_permlane32_swap_b32 %0, %1" : "+v"(a0), "+v"(b0));
        asm volatile("v_permlane32_swap_b32 %0, %1" : "+v"(a1), "+v"(b1));
        unsigned pw[4] = {a0, a1, b0, b1};
        const s16x8 pa = *(const s16x8*)pw;
#pragma unroll
        for (int d = 0; d < 4; ++d) {
          const s16x8 vbf = *(const s16x8*)&Vs[b][(d * 32 + l31) * 128 +
                                                 (((2 * S + hi) ^ (lane & 15)) * 8)];
          o[d] = __builtin_amdgcn_mfma_f32_32x32x16_bf16(pa, vbf, o[d], 0, 0, 0);
        }
      }
      __builtin_amdgcn_s_setprio(0);
      if (grp < 3) stc = stn;
    }
    __builtin_amdgcn_s_barrier();
    __builtin_amdgcn_sched_barrier(0);
  }

  sl += __shfl_xor(sl, 32);
  const float rs = 1.0f / sl;
#pragma unroll
  for (int r = 0; r < 16; ++r) {
    const float rq = __shfl(rs, CROW(r, hi));
    const int row = bx * 160 + w * 32 + CROW(r, hi);
    if (row < SEQ) {
#pragma unroll
      for (int d = 0; d < 4; ++d)
        AttO[(size_t)row * DIM + h * HD + d * 32 + l31] = f2bf(o[d][r] * rq);
    }
  }
}

// ---------------------------------------------------------------------------
extern "C" void kernel_launch(void* const* d_in, const int* in_sizes, int n_in,
                              void* d_out, int out_size, void* d_ws, size_t ws_size,
                              hipStream_t stream) {
  const float* x    = (const float*)d_in[0];
  const float* freqs= (const float*)d_in[1];
  const float* Wq   = (const float*)d_in[2];
  const float* bq   = (const float*)d_in[3];
  const float* gq   = (const float*)d_in[4];
  const float* Wk   = (const float*)d_in[5];
  const float* bk   = (const float*)d_in[6];
  const float* gk   = (const float*)d_in[7];
  const float* Wv   = (const float*)d_in[8];
  const float* bv   = (const float*)d_in[9];
  const float* Wo   = (const float*)d_in[10];
  const float* bo   = (const float*)d_in[11];
  const float* qkfb = (const float*)d_in[12];
  const float* vfb  = (const float*)d_in[13];
  const float* vsb  = (const float*)d_in[14];

  if (ws_size < (size_t)87705600) return;

  char* ws = (char*)d_ws;
  u16*   xb    = (u16*)(ws);               // [3200][1536] bf16
  u16*   Vt    = (u16*)(ws);               // alias: xb dead after QKV GEMM
  u16*   WtAll = (u16*)(ws + 9830400);     // [4608][1536] bf16 (Wq|Wk|Wv)^T
  u16*   WoT   = (u16*)(ws + 23986176);    // [1536][1536] bf16 Wo^T
  float* bcat  = (float*)(ws + 28704768);  // [4608]
  u16*   Pqkv  = (u16*)(ws + 28723200);    // [3200][4608] bf16
  u16*   AttO  = (u16*)(ws + 28723200);    // alias: Pqkv dead after k_post
  u16*   Qf    = (u16*)(ws + 58214400);    // [3200][1536] bf16
  u16*   Kf    = (u16*)(ws + 68044800);    // [3200][1536] bf16
  u16*   Vf    = (u16*)(ws + 77875200);    // [3200][1536] bf16

  k_prep<<<7104, 256, 0, stream>>>(x, bq, bk, bv, Wq, Wk, Wv, Wo,
                                   xb, bcat, WtAll, WoT);
  k_gemm<1><<<900, 256, 0, stream>>>(xb, WtAll, bcat, Pqkv, NQKV, DIM, SPAD, 36);
  k_post<<<SEQ, 256, 0, stream>>>(Pqkv, freqs, gq, gk, qkfb, vfb, vsb, Qf, Kf, Vf);
  k_transpose_v<<<dim3(50, 24), 256, 0, stream>>>(Vf, Vt);
  k_attn<<<240, 320, 0, stream>>>(Qf, Kf, Vt, AttO);
  k_gemm<0><<<300, 256, 0, stream>>>(AttO, WoT, bo, d_out, DIM, DIM, SEQ, 12);
}

// Round 18
// 232.404 us; speedup vs baseline: 1.0265x; 1.0265x over previous
//
#include <hip/hip_runtime.h>
#include <cstdint>

#define SEQ     3120
#define SPAD    3200
#define DIM     1536
#define NQKV    4608
#define HEADS   12
#define HD      128
#define SPATIAL 390
#define EPSV    1e-5f
#define KVBLK   128
#define NTILES  25
#define NEGBIG  (-1e30f)
// 1/sqrt(128) * log2(e): attention scores computed in log2 domain.
// FIXED-scale softmax (no running max): |s| <= ~12 in log2 domain, so
// exp2(s) <= 4096 and sum <= ~1e7 -- safely inside fp32; softmax is exactly
// scale-invariant, and bf16 relative precision is scale-free.
#define QSCALE  (0.08838834764831845f * 1.4426950408889634f)
#define CROW(r, hi) ((((r) & 3) + 8 * ((r) >> 2)) + 4 * (hi))

typedef unsigned short u16;
typedef short s16x8 __attribute__((ext_vector_type(8)));
typedef float f32x4 __attribute__((ext_vector_type(4)));
typedef float f32x16 __attribute__((ext_vector_type(16)));

__device__ __forceinline__ u16 f2bf(float f) {
  union { float f; unsigned u; } v; v.f = f;
  unsigned r = v.u + 0x7FFFu + ((v.u >> 16) & 1u);
  return (u16)(r >> 16);
}
__device__ __forceinline__ float bf2f(u16 b) {
  union { unsigned u; float f; } v; v.u = ((unsigned)b) << 16;
  return v.f;
}
__device__ __forceinline__ unsigned cvtpk(float lo, float hi) {
  unsigned r;
  asm("v_cvt_pk_bf16_f32 %0, %1, %2" : "=v"(r) : "v"(lo), "v"(hi));
  return r;
}
// async global->LDS, 16B per lane. LDS dest = wave-uniform base + lane*16.
__device__ __forceinline__ void gload16(const void* g, const void* l) {
  __builtin_amdgcn_global_load_lds(
      (const __attribute__((address_space(1))) unsigned*)g,
      (__attribute__((address_space(3))) unsigned*)(uintptr_t)l,
      16, 0, 0);
}

// ------- 1+2 fused prep: blocks [0,4800) convert x + biascat; -------------
//         blocks [4800,7104) transpose+convert the 4 weight matrices.
__global__ __launch_bounds__(256) void k_prep(
    const float* __restrict__ x, const float* __restrict__ bq,
    const float* __restrict__ bk, const float* __restrict__ bv,
    const float* __restrict__ Wq, const float* __restrict__ Wk,
    const float* __restrict__ Wv, const float* __restrict__ Wo,
    u16* __restrict__ xb, float* __restrict__ bcat,
    u16* __restrict__ WtAll, u16* __restrict__ WoT) {
  __shared__ float t[64][65];
  const int bid = blockIdx.x;
  if (bid < 4800) {
    // ---- convert x fp32 -> bf16, pad rows [SEQ,SPAD) with 0; biascat -----
    if (bid == 0) {
      for (int j = threadIdx.x; j < NQKV; j += 256)
        bcat[j] = (j < DIM) ? bq[j] : (j < 2 * DIM) ? bk[j - DIM] : bv[j - 2 * DIM];
    }
    const int i = (bid * 256 + threadIdx.x) * 4;
    if (i >= SPAD * DIM) return;
    const int row = i / DIM;
    float4 v = make_float4(0.f, 0.f, 0.f, 0.f);
    if (row < SEQ) v = *(const float4*)(x + i);
    const unsigned lo = (unsigned)f2bf(v.x) | ((unsigned)f2bf(v.y) << 16);
    const unsigned hi = (unsigned)f2bf(v.z) | ((unsigned)f2bf(v.w) << 16);
    *(uint2*)(xb + i) = make_uint2(lo, hi);
  } else {
    // ---- transpose weights: Wt[n][k] = W[k][n], 64x64 tiles --------------
    const int tb = bid - 4800;              // 0..2303
    const int wsel = tb / 576;              // 576 = 24*24
    const int rem = tb - wsel * 576;
    const int byi = rem / 24, bxi = rem - (rem / 24) * 24;
    const float* W = (wsel == 0) ? Wq : (wsel == 1) ? Wk : (wsel == 2) ? Wv : Wo;
    const int k0 = bxi * 64, n0 = byi * 64;
    const int c = threadIdx.x & 63, r4 = threadIdx.x >> 6;
#pragma unroll
    for (int rr = 0; rr < 64; rr += 4)
      t[r4 + rr][c] = W[(size_t)(k0 + r4 + rr) * DIM + n0 + c];
    __syncthreads();
    u16* Wt = (wsel < 3) ? (WtAll + (size_t)wsel * DIM * DIM) : WoT;
    const int kp = threadIdx.x & 31;
    const int r8 = threadIdx.x >> 5;
#pragma unroll
    for (int rr = 0; rr < 64; rr += 8) {
      const int n = r8 + rr;
      const unsigned v = (unsigned)f2bf(t[2 * kp][n]) |
                         ((unsigned)f2bf(t[2 * kp + 1][n]) << 16);
      *(unsigned*)&Wt[(size_t)(n0 + n) * DIM + k0 + 2 * kp] = v;
    }
  }
}

// ------- 4/8. bf16 MFMA GEMM, BK=64, dbuf + counted vmcnt (attn pattern) --
template <int OUT_BF16>
__global__ __launch_bounds__(256) void k_gemm(const u16* __restrict__ A,
                                              const u16* __restrict__ Bt,
                                              const float* __restrict__ bias,
                                              void* __restrict__ Cout,
                                              int N, int K, int storeMmax,
                                              int nbx) {
  __shared__ short As[2][8192];  // [128][64] swizzled
  __shared__ short Bs[2][8192];
  const int nwg = gridDim.x;
  const int q = nwg >> 3, r = nwg & 7;
  const int xcd = blockIdx.x & 7, idx = blockIdx.x >> 3;
  const int swz = (xcd < r ? xcd * (q + 1) : r * (q + 1) + (xcd - r) * q) + idx;
  const int bxi = swz % nbx, byi = swz / nbx;
  const int brow = byi * 128, bcol = bxi * 128;

  const int tid = threadIdx.x;
  const int lane = tid & 63, wv = tid >> 6;
  const int l15 = lane & 15, g = lane >> 4;
  const int wr = wv >> 1, wc = wv & 1;

  const f32x4 z4 = {0.f, 0.f, 0.f, 0.f};
  f32x4 acc[4][4];
#pragma unroll
  for (int m = 0; m < 4; ++m)
#pragma unroll
    for (int n = 0; n < 4; ++n) acc[m][n] = z4;

  const u16* Ap[4];
  const u16* Bp[4];
  const int sch = ((lane & 7) ^ ((lane >> 3) & 7)) * 8;
#pragma unroll
  for (int it = 0; it < 4; ++it) {
    const int row = it * 32 + wv * 8 + (lane >> 3);
    Ap[it] = A + (size_t)(brow + row) * K + sch;
    Bp[it] = Bt + (size_t)(bcol + row) * K + sch;
  }
  auto stage = [&](int T, int B) {
    const int k0 = T * 64;
#pragma unroll
    for (int it = 0; it < 4; ++it) {
      gload16(Ap[it] + k0, &As[B][(it * 32 + wv * 8) * 64]);
      gload16(Bp[it] + k0, &Bs[B][(it * 32 + wv * 8) * 64]);
    }
  };

  const int NK = K >> 6;
  stage(0, 0);

  for (int t = 0; t < NK; ++t) {
    const int b = t & 1;
    if (t + 1 < NK) {
      stage(t + 1, b ^ 1);
      asm volatile("s_waitcnt vmcnt(8)" ::: "memory");  // tile t's 8 done
    } else {
      asm volatile("s_waitcnt vmcnt(0)" ::: "memory");
    }
    __builtin_amdgcn_s_barrier();
    __builtin_amdgcn_sched_barrier(0);
#pragma unroll
    for (int kk = 0; kk < 2; ++kk) {
      s16x8 a[4], bfr[4];
#pragma unroll
      for (int m = 0; m < 4; ++m)
        a[m] = *(const s16x8*)&As[b][(wr * 64 + m * 16 + l15) * 64 +
                                     (((kk * 4 + g) ^ (l15 & 7)) * 8)];
#pragma unroll
      for (int n = 0; n < 4; ++n)
        bfr[n] = *(const s16x8*)&Bs[b][(wc * 64 + n * 16 + l15) * 64 +
                                       (((kk * 4 + g) ^ (l15 & 7)) * 8)];
#pragma unroll
      for (int m = 0; m < 4; ++m)
#pragma unroll
        for (int n = 0; n < 4; ++n)
          acc[m][n] = __builtin_amdgcn_mfma_f32_16x16x32_bf16(a[m], bfr[n], acc[m][n], 0, 0, 0);
    }
    __builtin_amdgcn_s_barrier();  // protect buf b before stage(t+2) writes it
    __builtin_amdgcn_sched_barrier(0);
  }

#pragma unroll
  for (int m = 0; m < 4; ++m) {
#pragma unroll
    for (int n = 0; n < 4; ++n) {
      const int cc = bcol + wc * 64 + n * 16 + l15;
      const float bb = bias[cc];
#pragma unroll
      for (int i = 0; i < 4; ++i) {
        const int rr = brow + wr * 64 + m * 16 + g * 4 + i;
        if (rr < storeMmax) {
          const float v = acc[m][n][i] + bb;
          if (OUT_BF16) ((u16*)Cout)[(size_t)rr * N + cc] = f2bf(v);
          else          ((float*)Cout)[(size_t)rr * N + cc] = v;
        }
      }
    }
  }
}

// ---------------- 5. per-token: rmsnorm + rope + biases (vectorized) -------
__global__ __launch_bounds__(256) void k_post(
    const u16* __restrict__ Pqkv, const float* __restrict__ freqs,
    const float* __restrict__ gq, const float* __restrict__ gk,
    const float* __restrict__ qkfb, const float* __restrict__ vfb,
    const float* __restrict__ vsb,
    u16* __restrict__ Qf, u16* __restrict__ Kf, u16* __restrict__ Vf) {
  const int s = blockIdx.x;
  const int t = threadIdx.x;
  const int fidx = s / SPATIAL;
  const int sp = s - fidx * SPATIAL;
  __shared__ float cs[64], sn[64];
  __shared__ float red[8];
  if (t < 64) {
    const float a = freqs[s * 64 + t];
    cs[t] = __cosf(a);
    sn[t] = __sinf(a);
  }
  const u16* qrow = Pqkv + (size_t)s * NQKV;
  const u16* krow = qrow + DIM;
  const u16* vrow = qrow + 2 * DIM;
  s16x8 q8, k8, v8;
  float sq = 0.f, sk = 0.f;
  if (t < 192) {
    q8 = *(const s16x8*)(qrow + 8 * t);
    k8 = *(const s16x8*)(krow + 8 * t);
    v8 = *(const s16x8*)(vrow + 8 * t);
#pragma unroll
    for (int i = 0; i < 8; ++i) {
      const float a = bf2f((u16)q8[i]); sq += a * a;
      const float b = bf2f((u16)k8[i]); sk += b * b;
    }
  }
#pragma unroll
  for (int off = 1; off < 64; off <<= 1) {
    sq += __shfl_xor(sq, off);
    sk += __shfl_xor(sk, off);
  }
  const int lane = t & 63, wv = t >> 6;
  if (lane == 0) { red[wv] = sq; red[wv + 4] = sk; }
  __syncthreads();
  sq = red[0] + red[1] + red[2] + red[3];
  sk = red[4] + red[5] + red[6] + red[7];
  const float rq = rsqrtf(sq * (1.0f / DIM) + EPSV);
  const float rk = rsqrtf(sk * (1.0f / DIM) + EPSV);
  if (t >= 192) return;
  const int d0 = 8 * t;
  float GQ[8], GK[8], FB[8], VF[8], VS[8];
  *(float4*)&GQ[0] = *(const float4*)(gq + d0);
  *(float4*)&GQ[4] = *(const float4*)(gq + d0 + 4);
  *(float4*)&GK[0] = *(const float4*)(gk + d0);
  *(float4*)&GK[4] = *(const float4*)(gk + d0 + 4);
  *(float4*)&FB[0] = *(const float4*)(qkfb + fidx * DIM + d0);
  *(float4*)&FB[4] = *(const float4*)(qkfb + fidx * DIM + d0 + 4);
  *(float4*)&VF[0] = *(const float4*)(vfb + fidx * DIM + d0);
  *(float4*)&VF[4] = *(const float4*)(vfb + fidx * DIM + d0 + 4);
  *(float4*)&VS[0] = *(const float4*)(vsb + (size_t)sp * DIM + d0);
  *(float4*)&VS[4] = *(const float4*)(vsb + (size_t)sp * DIM + d0 + 4);
  unsigned qo[4], ko[4], vo[4];
#pragma unroll
  for (int pi = 0; pi < 4; ++pi) {
    const int pin = (4 * t + pi) & 63;
    const float c = cs[pin], s_ = sn[pin];
    float xr = bf2f((u16)q8[2 * pi]) * rq * GQ[2 * pi];
    float xi = bf2f((u16)q8[2 * pi + 1]) * rq * GQ[2 * pi + 1];
    const float q0 = (xr * c - xi * s_ + FB[2 * pi]) * QSCALE;
    const float q1 = (xr * s_ + xi * c + FB[2 * pi + 1]) * QSCALE;
    qo[pi] = (unsigned)f2bf(q0) | ((unsigned)f2bf(q1) << 16);
    xr = bf2f((u16)k8[2 * pi]) * rk * GK[2 * pi];
    xi = bf2f((u16)k8[2 * pi + 1]) * rk * GK[2 * pi + 1];
    const float kk0 = xr * c - xi * s_ + FB[2 * pi];
    const float kk1 = xr * s_ + xi * c + FB[2 * pi + 1];
    ko[pi] = (unsigned)f2bf(kk0) | ((unsigned)f2bf(kk1) << 16);
    const float v0 = bf2f((u16)v8[2 * pi]) + VF[2 * pi] + VS[2 * pi];
    const float v1 = bf2f((u16)v8[2 * pi + 1]) + VF[2 * pi + 1] + VS[2 * pi + 1];
    vo[pi] = (unsigned)f2bf(v0) | ((unsigned)f2bf(v1) << 16);
  }
  *(uint4*)(Qf + (size_t)s * DIM + d0) = make_uint4(qo[0], qo[1], qo[2], qo[3]);
  *(uint4*)(Kf + (size_t)s * DIM + d0) = make_uint4(ko[0], ko[1], ko[2], ko[3]);
  *(uint4*)(Vf + (size_t)s * DIM + d0) = make_uint4(vo[0], vo[1], vo[2], vo[3]);
}

// ---------------- 6. V transpose: Vf[s][1536] -> Vt[dglob][SPAD] -----------
__global__ __launch_bounds__(256) void k_transpose_v(const u16* __restrict__ Vf,
                                                     u16* __restrict__ Vt) {
  __shared__ u16 tile[64][65];
  const int s0 = blockIdx.x * 64, c0 = blockIdx.y * 64;
  const int c = threadIdx.x & 63, r4 = threadIdx.x >> 6;
#pragma unroll
  for (int rr = 0; rr < 64; rr += 4) {
    const int s = s0 + r4 + rr;
    tile[r4 + rr][c] = (s < SEQ) ? Vf[(size_t)s * DIM + c0 + c] : (u16)0;
  }
  __syncthreads();
#pragma unroll
  for (int rr = 0; rr < 64; rr += 4) {
    const int dglob = c0 + r4 + rr;
    Vt[(size_t)dglob * SPAD + s0 + c] = tile[c][r4 + rr];
  }
}

// ---------------- 7. flash attention: KVBLK=128, per-group (R16 exact) -----
// 1D grid 240: gb = (bid&7)*30 + (bid>>3); h = gb/20, bx = gb%20 (R13:
// FETCH 80->18MB). Fixed-scale softmax is order-free: each 128-key tile is
// processed as 4 independent 32-key groups {8 QK MFMA -> exp2/pack ->
// permlane -> 8 PV MFMA}; the compiler's own interleave of consecutive
// groups beats manual 2-stage pipelining (R17: T15 regressed 107.6->114.5,
// consistent with m253 -- do not re-add). Conflict-free LDS:
// K [128 key][16 ch][8] ch^=key&15; V^T [128 d][16 ch][8] ch^=d&15.
__global__ __launch_bounds__(320, 2) void k_attn(const u16* __restrict__ Qf,
                                                 const u16* __restrict__ Kf,
                                                 const u16* __restrict__ Vt,
                                                 u16* __restrict__ AttO) {
  __shared__ short Ks[2][16384];  // [128 key][16 chunk][8]
  __shared__ short Vs[2][16384];  // [128 d][16 chunk][8]
  const int bid = blockIdx.x;
  const int gb = (bid & 7) * 30 + (bid >> 3);
  const int h = gb / 20;
  const int bx = gb - h * 20;
  const int tid = threadIdx.x;
  const int lane = tid & 63, w = tid >> 6;     // w in 0..4
  const int l31 = lane & 31, hi = lane >> 5;
  const int qrow = bx * 160 + w * 32 + l31;

  // Q B-frags: qb[s] = Q[qrow][16s + 8hi + j]
  s16x8 qb[8];
  {
    const u16* qp = Qf + (size_t)qrow * DIM + h * HD + hi * 8;
#pragma unroll
    for (int s = 0; s < 8; ++s) qb[s] = *(const s16x8*)(qp + s * 16);
  }

  f32x16 o[4];
#pragma unroll
  for (int d = 0; d < 4; ++d)
#pragma unroll
    for (int r = 0; r < 16; ++r) o[d][r] = 0.f;
  float sl = 0.f;

  // staging pointers (warps 0..3: each stages 32 K-rows + 32 V-rows)
  const u16* Kp[8];
  const u16* Vp[8];
  if (w < 4) {
#pragma unroll
    for (int it = 0; it < 8; ++it) {
      const int krow = w * 32 + it * 4 + (lane >> 4);
      const int kch = (lane & 15) ^ (krow & 15);
      Kp[it] = Kf + (size_t)krow * DIM + h * HD + kch * 8;
      const int vrow = w * 32 + it * 4 + (lane >> 4);
      const int vch = (lane & 15) ^ (vrow & 15);
      Vp[it] = Vt + (size_t)(h * HD + vrow) * SPAD + vch * 8;
    }
  }
  auto stage = [&](int T, int B) {
    const size_t kof = (size_t)T * KVBLK * DIM;
    const int vof = T * KVBLK;
#pragma unroll
    for (int it = 0; it < 8; ++it) {
      gload16(Kp[it] + kof, &Ks[B][(w * 32 + it * 4) * 128]);
      gload16(Vp[it] + vof, &Vs[B][(w * 32 + it * 4) * 128]);
    }
  };

  if (w < 4) {
    asm volatile("s_waitcnt vmcnt(0)" ::: "memory");
    stage(0, 0);
  }

  for (int t = 0; t < NTILES; ++t) {
    const int b = t & 1;
    if (w < 4) {
      if (t + 1 < NTILES) {
        stage(t + 1, b ^ 1);
        asm volatile("s_waitcnt vmcnt(16)" ::: "memory");  // tile t's 16 done
      } else {
        asm volatile("s_waitcnt vmcnt(0)" ::: "memory");
      }
    }
    __builtin_amdgcn_s_barrier();
    __builtin_amdgcn_sched_barrier(0);

    // 4 independent 32-key groups: QK -> softmax -> PV per group
#pragma unroll
    for (int grp = 0; grp < 4; ++grp) {
      // S^T = K Q  (D[key][q]: col q = l31, row key = grp*32 + CROW(r,hi))
      f32x16 st;
#pragma unroll
      for (int r = 0; r < 16; ++r) st[r] = 0.f;
      __builtin_amdgcn_s_setprio(1);
#pragma unroll
      for (int s = 0; s < 8; ++s) {
        const s16x8 ka = *(const s16x8*)&Ks[b][(grp * 32 + l31) * 128 +
                                              (((2 * s + hi) ^ (lane & 15)) * 8)];
        st = __builtin_amdgcn_mfma_f32_32x32x16_bf16(ka, qb[s], st, 0, 0, 0);
      }
      __builtin_amdgcn_s_setprio(0);

      if (t == NTILES - 1) {  // tile 24: keys >= 3120 invalid
        if (grp == 1) {
#pragma unroll
          for (int r = 8; r < 16; ++r) st[r] = NEGBIG;   // keys 3120..3135
        } else if (grp >= 2) {
#pragma unroll
          for (int r = 0; r < 16; ++r) st[r] = NEGBIG;   // keys 3136..3199
        }
      }
      // P = exp2(S): fixed scale, lane-local sums, pack bf16
      unsigned W[8];
      float p0s = 0.f, p1s = 0.f;
#pragma unroll
      for (int i = 0; i < 8; ++i) {
        const float p0 = exp2f(st[2 * i]);
        const float p1 = exp2f(st[2 * i + 1]);
        p0s += p0; p1s += p1;
        W[i] = cvtpk(p0, p1);
      }
      sl += p0s + p1s;

      // O += P V  (partner exchange via permlane32_swap, VALU not LDS)
      __builtin_amdgcn_s_setprio(1);
#pragma unroll
      for (int s2 = 0; s2 < 2; ++s2) {
        const int S = grp * 2 + s2;        // global key-slice (16 keys)
        unsigned a0 = W[s2 * 4 + 0], b0 = W[s2 * 4 + 2];
        unsigned a1 = W[s2 * 4 + 1], b1 = W[s2 * 4 + 3];
        asm volatile("v_permlane32_swap_b32 %0, %1" : "+v"(a0), "+v"(b0));
        asm volatile("v_permlane32_swap_b32 %0, %1" : "+v"(a1), "+v"(b1));
        unsigned pw[4] = {a0, a1, b0, b1};
        const s16x8 pa = *(const s16x8*)pw;
#pragma unroll
        for (int d = 0; d < 4; ++d) {
          const s16x8 vbf = *(const s16x8*)&Vs[b][(d * 32 + l31) * 128 +
                                                 (((2 * S + hi) ^ (lane & 15)) * 8)];
          o[d] = __builtin_amdgcn_mfma_f32_32x32x16_bf16(pa, vbf, o[d], 0, 0, 0);
        }
      }
      __builtin_amdgcn_s_setprio(0);
    }
    __builtin_amdgcn_s_barrier();
    __builtin_amdgcn_sched_barrier(0);
  }

  sl += __shfl_xor(sl, 32);
  const float rs = 1.0f / sl;
#pragma unroll
  for (int r = 0; r < 16; ++r) {
    const float rq = __shfl(rs, CROW(r, hi));
    const int row = bx * 160 + w * 32 + CROW(r, hi);
    if (row < SEQ) {
#pragma unroll
      for (int d = 0; d < 4; ++d)
        AttO[(size_t)row * DIM + h * HD + d * 32 + l31] = f2bf(o[d][r] * rq);
    }
  }
}

// ---------------------------------------------------------------------------
extern "C" void kernel_launch(void* const* d_in, const int* in_sizes, int n_in,
                              void* d_out, int out_size, void* d_ws, size_t ws_size,
                              hipStream_t stream) {
  const float* x    = (const float*)d_in[0];
  const float* freqs= (const float*)d_in[1];
  const float* Wq   = (const float*)d_in[2];
  const float* bq   = (const float*)d_in[3];
  const float* gq   = (const float*)d_in[4];
  const float* Wk   = (const float*)d_in[5];
  const float* bk   = (const float*)d_in[6];
  const float* gk   = (const float*)d_in[7];
  const float* Wv   = (const float*)d_in[8];
  const float* bv   = (const float*)d_in[9];
  const float* Wo   = (const float*)d_in[10];
  const float* bo   = (const float*)d_in[11];
  const float* qkfb = (const float*)d_in[12];
  const float* vfb  = (const float*)d_in[13];
  const float* vsb  = (const float*)d_in[14];

  if (ws_size < (size_t)87705600) return;

  char* ws = (char*)d_ws;
  u16*   xb    = (u16*)(ws);               // [3200][1536] bf16
  u16*   Vt    = (u16*)(ws);               // alias: xb dead after QKV GEMM
  u16*   WtAll = (u16*)(ws + 9830400);     // [4608][1536] bf16 (Wq|Wk|Wv)^T
  u16*   WoT   = (u16*)(ws + 23986176);    // [1536][1536] bf16 Wo^T
  float* bcat  = (float*)(ws + 28704768);  // [4608]
  u16*   Pqkv  = (u16*)(ws + 28723200);    // [3200][4608] bf16
  u16*   AttO  = (u16*)(ws + 28723200);    // alias: Pqkv dead after k_post
  u16*   Qf    = (u16*)(ws + 58214400);    // [3200][1536] bf16
  u16*   Kf    = (u16*)(ws + 68044800);    // [3200][1536] bf16
  u16*   Vf    = (u16*)(ws + 77875200);    // [3200][1536] bf16

  k_prep<<<7104, 256, 0, stream>>>(x, bq, bk, bv, Wq, Wk, Wv, Wo,
                                   xb, bcat, WtAll, WoT);
  k_gemm<1><<<900, 256, 0, stream>>>(xb, WtAll, bcat, Pqkv, NQKV, DIM, SPAD, 36);
  k_post<<<SEQ, 256, 0, stream>>>(Pqkv, freqs, gq, gk, qkfb, vfb, vsb, Qf, Kf, Vf);
  k_transpose_v<<<dim3(50, 24), 256, 0, stream>>>(Vf, Vt);
  k_attn<<<240, 320, 0, stream>>>(Qf, Kf, Vt, AttO);
  k_gemm<0><<<300, 256, 0, stream>>>(AttO, WoT, bo, d_out, DIM, DIM, SEQ, 12);
}